// Round 6
// baseline (251.215 us; speedup 1.0000x reference)
//
#include <hip/hip_runtime.h>

typedef __bf16 bf16x8 __attribute__((ext_vector_type(8)));
typedef float f32x4 __attribute__((ext_vector_type(4)));
typedef unsigned int u32x4 __attribute__((ext_vector_type(4)));
typedef unsigned int u32x2 __attribute__((ext_vector_type(2)));
typedef u32x4 u32x4a __attribute__((may_alias));
typedef u32x2 u32x2a __attribute__((may_alias));
typedef f32x4 f32x4a __attribute__((may_alias));
typedef unsigned int u32a __attribute__((may_alias));

#define NITER 8   // per wave: 8 iters x 2 tiles x 16 pts = 256 pts; block(4 waves) = 1024 pts
#define STR 88    // s_h row stride in shorts: 176B = 16B-aligned; dword-stride 44 -> start bank
                  // 4*(3*pp+q)%32 uniform over all 8 groups => b128 at exact 8-phase floor

__device__ inline unsigned short f2b(float f) {  // f32 -> bf16 RNE
    unsigned int x;
    __builtin_memcpy(&x, &f, 4);
    unsigned int r = (x + 0x7FFFu + ((x >> 16) & 1u)) >> 16;
    return (unsigned short)r;
}
__device__ inline unsigned int pack_rne(float a, float b) {  // RNE bf16x2 (feature path)
    return (unsigned int)f2b(a) | ((unsigned int)f2b(b) << 16);
}
__device__ inline unsigned int cvt_pk_bf16(float lo, float hi) {  // HW pack (softplus outputs)
    unsigned int r;
    asm("v_cvt_pk_bf16_f32 %0, %1, %2" : "=v"(r) : "v"(lo), "v"(hi));
    return r;
}
// round-4 proven numerics
__device__ inline float softplus_f(float x) {
    return fmaxf(x, 0.f) + __logf(1.f + __expf(-fabsf(x)));
}
__device__ inline float sigmoid_f(float x) {     // accurate division (not rcp)
    return 1.f / (1.f + __expf(-x));
}
__device__ inline bf16x8 as_bf16x8(u32x4 v) { return __builtin_bit_cast(bf16x8, v); }

// ws layout: [0..287] f32 biases | byte 1152: ushort frag-major weights 36*64*8
// bias map: [0]ob0 [64]ob1 [128]ob2 [144]rb1 [208]rb2(pad->16) [224]rgb_b0'(folded latent)
// frag bases: occ0:0(Nt4,Kt1) occ1:4(4,2) occ2:12(1,2) rgb0:14(4,3) rgb1:26(4,2) rgb2:34(1,2)
// frag: lane l holds W[k=kt*32+(l>>4)*8+j][n=nt*16+(l&15)]
// rgb0 x-row map: k<32 emb, 32..58 dir, 59..64 zero, k=65..79 -> feat rows 59..73, k>=80 zero
//                 (feat k-index == raw occ2 output index + 64; out0=occ-preact nulled by zero row)

__global__ __launch_bounds__(256) void prep_weights(
    const float* __restrict__ oW0, const float* __restrict__ ob0,
    const float* __restrict__ oW1, const float* __restrict__ ob1,
    const float* __restrict__ oW2, const float* __restrict__ ob2,
    const float* __restrict__ rW0, const float* __restrict__ rb0,
    const float* __restrict__ rW1, const float* __restrict__ rb1,
    const float* __restrict__ rW2, const float* __restrict__ rb2,
    const float* __restrict__ rlat, const int* __restrict__ lidx,
    float* __restrict__ wsf, ushort* __restrict__ wsw)
{
    const int bid = blockIdx.x, tid = threadIdx.x;
    __shared__ float red[256];

    if (bid == 0) {
        for (int i = tid; i < 224; i += 256) {
            float v;
            if (i < 64)       v = ob0[i];
            else if (i < 128) v = ob1[i - 64];
            else if (i < 144) v = ob2[i - 128];
            else if (i < 208) v = rb1[i - 144];
            else              v = (i - 208 < 3) ? rb2[i - 208] : 0.f;
            wsf[i] = v;
        }
    }
    if (bid == 7) {  // parallel latent fold: rgb_b0' = rgb_b0 + latent @ rgb_W0[74:202]
        const int outn = tid & 63, sl = tid >> 6;
        const float* lat = rlat + (size_t)lidx[0] * 128;
        float p = 0.f;
        for (int k = sl * 32; k < sl * 32 + 32; k++)
            p = fmaf(lat[k], rW0[(74 + k) * 64 + outn], p);
        red[tid] = p;
        __syncthreads();
        if (tid < 64)
            wsf[224 + tid] = rb0[tid] + red[tid] + red[64 + tid] + red[128 + tid] + red[192 + tid];
    }
    for (int t = tid; t < 288; t += 256) {
        const int s = bid * 288 + t;
        const int frag = s >> 6, lane = s & 63;
        const int qq = lane >> 4, cc = lane & 15;
        const float* W;
        int ldn = 64, nt = 0, kt = 0;
        bool isr0 = false, isr2 = false;
        if (frag < 4)       { W = oW0; nt = frag; kt = 0; }
        else if (frag < 12) { W = oW1; int f = frag - 4;  nt = f >> 1; kt = f & 1; }
        else if (frag < 14) { W = oW2; ldn = 16; nt = 0; kt = frag - 12; }
        else if (frag < 26) { W = rW0; int f = frag - 14; nt = f / 3; kt = f - nt * 3; isr0 = true; }
        else if (frag < 34) { W = rW1; int f = frag - 26; nt = f >> 1; kt = f & 1; }
        else                { W = rW2; ldn = 3; nt = 0; kt = frag - 34; isr2 = true; }
        const int nn = nt * 16 + cc;
        __align__(16) ushort vals[8];
#pragma unroll
        for (int j = 0; j < 8; j++) {
            int k = kt * 32 + qq * 8 + j;
            float v = 0.f;
            if (isr0) {
                int ks = -1;
                if (k < 59) ks = k;
                else if (k >= 65 && k < 80) ks = k - 65 + 59;
                if (ks >= 0) v = W[ks * 64 + nn];
            } else if (isr2) {
                if (nn < 3) v = W[k * 3 + nn];
            } else {
                v = W[k * ldn + nn];
            }
            vals[j] = f2b(v);
        }
        *(u32x4a*)&wsw[s * 8] = *(const u32x4a*)vals;
    }
}

// Transposed-compute: D = W^T_tile . X^T_tile (row=out, col=point).
// Each wave processes TWO 16-pt tiles per iter; weight frags loaded once, used twice.
__global__ __launch_bounds__(256, 2) void net_mfma(
    const float* __restrict__ emb, const float* __restrict__ dir,
    const float* __restrict__ wsf, const ushort* __restrict__ wsw,
    float* __restrict__ out, int n)
{
    __shared__ __align__(16) ushort s_w[36 * 64 * 8];   // 36,864 B
    __shared__ __align__(16) ushort s_h[4][32 * STR];   // 22,528 B (32 pts/wave, stride 88)

    const int tid = threadIdx.x;
    for (int i = tid; i < 36 * 64; i += 256)
        *(u32x4a*)&s_w[i * 8] = *(const u32x4a*)(wsw + i * 8);
    __syncthreads();

    const int wave = tid >> 6, lane = tid & 63, q = lane >> 4, c = lane & 15;
    const int q4 = q * 4;
    ushort* hw = s_h[wave];
    // zero own slice once (stale LDS could be NaN-patterned bf16)
    for (int i = lane; i < 32 * STR / 2; i += 64) ((u32a*)hw)[i] = 0u;

    const int rowA = c * STR, rowB = (16 + c) * STR;   // tile0/tile1 rows for this lane

    // biases resident in VGPRs (18 x f32x4)
    f32x4 Bv[18];
#pragma unroll
    for (int nt = 0; nt < 4; nt++) {
        Bv[0 + nt]  = *(const f32x4a*)(wsf + 0   + nt * 16 + q4);  // occ0
        Bv[4 + nt]  = *(const f32x4a*)(wsf + 64  + nt * 16 + q4);  // occ1
        Bv[9 + nt]  = *(const f32x4a*)(wsf + 224 + nt * 16 + q4);  // rgb0'
        Bv[13 + nt] = *(const f32x4a*)(wsf + 144 + nt * 16 + q4);  // rgb1
    }
    Bv[8]  = *(const f32x4a*)(wsf + 128 + q4);  // occ2
    Bv[17] = *(const f32x4a*)(wsf + 208 + q4);  // rgb2

    const long dlim = (long)n * 27;

    for (int it = 0; it < NITER; ++it) {
        const long p0 = (long)blockIdx.x * 1024 + it * 128 + wave * 32;
        const long ptA = p0 + c, ptB = p0 + 16 + c;

        // ---- input B-fragments straight from global (both tiles) ----
        bf16x8 xe[2], xd[2];
#pragma unroll
        for (int t = 0; t < 2; t++) {
            const long pt = t ? ptB : ptA;
            {
                const float* ep = emb + pt * 32 + q * 8;
                f32x4 e0 = *(const f32x4a*)ep;
                f32x4 e1 = *(const f32x4a*)(ep + 4);
                u32x4 pk = {cvt_pk_bf16(e0[0], e0[1]), cvt_pk_bf16(e0[2], e0[3]),
                            cvt_pk_bf16(e1[0], e1[1]), cvt_pk_bf16(e1[2], e1[3])};
                xe[t] = as_bf16x8(pk);
            }
            {
                const long ib = pt * 27 + q * 8;
                f32x4 d0, d1;
                if (ib + 8 <= dlim) {
                    d0 = *(const f32x4a*)(dir + ib);
                    d1 = *(const f32x4a*)(dir + ib + 4);
                } else {
#pragma unroll
                    for (int j = 0; j < 4; j++) d0[j] = (ib + j < dlim) ? dir[ib + j] : 0.f;
#pragma unroll
                    for (int j = 0; j < 4; j++) d1[j] = (ib + 4 + j < dlim) ? dir[ib + 4 + j] : 0.f;
                }
                // k-local >= 27 garbage: rgb0/occ-dir weight rows 27..31 are zero
                u32x4 pk = {cvt_pk_bf16(d0[0], d0[1]), cvt_pk_bf16(d0[2], d0[3]),
                            cvt_pk_bf16(d1[0], d1[1]), cvt_pk_bf16(d1[2], d1[3])};
                xd[t] = as_bf16x8(pk);
            }
        }

        // ---- occ layer 0: K=32 (emb), out 64 ----
#pragma unroll
        for (int nt = 0; nt < 4; ++nt) {
            bf16x8 w = as_bf16x8(*(const u32x4a*)&s_w[((0 + nt) * 64 + lane) * 8]);
            f32x4 aA = __builtin_amdgcn_mfma_f32_16x16x32_bf16(w, xe[0], Bv[0 + nt], 0, 0, 0);
            f32x4 aB = __builtin_amdgcn_mfma_f32_16x16x32_bf16(w, xe[1], Bv[0 + nt], 0, 0, 0);
            *(u32x2a*)&hw[rowA + nt * 16 + q4] = u32x2{
                cvt_pk_bf16(softplus_f(aA[0]), softplus_f(aA[1])),
                cvt_pk_bf16(softplus_f(aA[2]), softplus_f(aA[3]))};
            *(u32x2a*)&hw[rowB + nt * 16 + q4] = u32x2{
                cvt_pk_bf16(softplus_f(aB[0]), softplus_f(aB[1])),
                cvt_pk_bf16(softplus_f(aB[2]), softplus_f(aB[3]))};
        }
        // ---- occ layer 1: K=64, out 64 ----
        {
            bf16x8 h0A = as_bf16x8(*(const u32x4a*)&hw[rowA + 0 + q * 8]);
            bf16x8 h1A = as_bf16x8(*(const u32x4a*)&hw[rowA + 32 + q * 8]);
            bf16x8 h0B = as_bf16x8(*(const u32x4a*)&hw[rowB + 0 + q * 8]);
            bf16x8 h1B = as_bf16x8(*(const u32x4a*)&hw[rowB + 32 + q * 8]);
#pragma unroll
            for (int nt = 0; nt < 4; ++nt) {
                bf16x8 w0 = as_bf16x8(*(const u32x4a*)&s_w[((4 + nt * 2 + 0) * 64 + lane) * 8]);
                bf16x8 w1 = as_bf16x8(*(const u32x4a*)&s_w[((4 + nt * 2 + 1) * 64 + lane) * 8]);
                f32x4 aA = __builtin_amdgcn_mfma_f32_16x16x32_bf16(w0, h0A, Bv[4 + nt], 0, 0, 0);
                aA = __builtin_amdgcn_mfma_f32_16x16x32_bf16(w1, h1A, aA, 0, 0, 0);
                f32x4 aB = __builtin_amdgcn_mfma_f32_16x16x32_bf16(w0, h0B, Bv[4 + nt], 0, 0, 0);
                aB = __builtin_amdgcn_mfma_f32_16x16x32_bf16(w1, h1B, aB, 0, 0, 0);
                *(u32x2a*)&hw[rowA + nt * 16 + q4] = u32x2{
                    cvt_pk_bf16(softplus_f(aA[0]), softplus_f(aA[1])),
                    cvt_pk_bf16(softplus_f(aA[2]), softplus_f(aA[3]))};
                *(u32x2a*)&hw[rowB + nt * 16 + q4] = u32x2{
                    cvt_pk_bf16(softplus_f(aB[0]), softplus_f(aB[1])),
                    cvt_pk_bf16(softplus_f(aB[2]), softplus_f(aB[3]))};
            }
        }
        // ---- occ layer 2: K=64, out 16 (raw -> feat k=0..15; occ = sigmoid(out0)) ----
        float occA, occB;
        {
            bf16x8 h0A = as_bf16x8(*(const u32x4a*)&hw[rowA + 0 + q * 8]);
            bf16x8 h1A = as_bf16x8(*(const u32x4a*)&hw[rowA + 32 + q * 8]);
            bf16x8 h0B = as_bf16x8(*(const u32x4a*)&hw[rowB + 0 + q * 8]);
            bf16x8 h1B = as_bf16x8(*(const u32x4a*)&hw[rowB + 32 + q * 8]);
            bf16x8 w0 = as_bf16x8(*(const u32x4a*)&s_w[(12 * 64 + lane) * 8]);
            bf16x8 w1 = as_bf16x8(*(const u32x4a*)&s_w[(13 * 64 + lane) * 8]);
            f32x4 aA = __builtin_amdgcn_mfma_f32_16x16x32_bf16(w0, h0A, Bv[8], 0, 0, 0);
            aA = __builtin_amdgcn_mfma_f32_16x16x32_bf16(w1, h1A, aA, 0, 0, 0);
            f32x4 aB = __builtin_amdgcn_mfma_f32_16x16x32_bf16(w0, h0B, Bv[8], 0, 0, 0);
            aB = __builtin_amdgcn_mfma_f32_16x16x32_bf16(w1, h1B, aB, 0, 0, 0);
            occA = sigmoid_f(aA[0]);  // 1-exp(-softplus(h)) == sigmoid(h); valid on q==0
            occB = sigmoid_f(aB[0]);
            // feature is LINEAR and error-amplified downstream: explicit RNE pack
            *(u32x2a*)&hw[rowA + q4] = u32x2{pack_rne(aA[0], aA[1]), pack_rne(aA[2], aA[3])};
            *(u32x2a*)&hw[rowB + q4] = u32x2{pack_rne(aB[0], aB[1]), pack_rne(aB[2], aB[3])};
        }
        // ---- rgb layer 0: K=96 (emb|dir|feat), out 64, bias = folded rgb_b0' ----
        {
            // k-local 16..31 of feat tile = stale finite activations x zero weight rows
            bf16x8 xfA = as_bf16x8(*(const u32x4a*)&hw[rowA + q * 8]);
            bf16x8 xfB = as_bf16x8(*(const u32x4a*)&hw[rowB + q * 8]);
#pragma unroll
            for (int nt = 0; nt < 4; ++nt) {
                bf16x8 w0 = as_bf16x8(*(const u32x4a*)&s_w[((14 + nt * 3 + 0) * 64 + lane) * 8]);
                bf16x8 w1 = as_bf16x8(*(const u32x4a*)&s_w[((14 + nt * 3 + 1) * 64 + lane) * 8]);
                bf16x8 w2 = as_bf16x8(*(const u32x4a*)&s_w[((14 + nt * 3 + 2) * 64 + lane) * 8]);
                f32x4 aA = __builtin_amdgcn_mfma_f32_16x16x32_bf16(w0, xe[0], Bv[9 + nt], 0, 0, 0);
                aA = __builtin_amdgcn_mfma_f32_16x16x32_bf16(w1, xd[0], aA, 0, 0, 0);
                aA = __builtin_amdgcn_mfma_f32_16x16x32_bf16(w2, xfA, aA, 0, 0, 0);
                f32x4 aB = __builtin_amdgcn_mfma_f32_16x16x32_bf16(w0, xe[1], Bv[9 + nt], 0, 0, 0);
                aB = __builtin_amdgcn_mfma_f32_16x16x32_bf16(w1, xd[1], aB, 0, 0, 0);
                aB = __builtin_amdgcn_mfma_f32_16x16x32_bf16(w2, xfB, aB, 0, 0, 0);
                *(u32x2a*)&hw[rowA + nt * 16 + q4] = u32x2{
                    cvt_pk_bf16(softplus_f(aA[0]), softplus_f(aA[1])),
                    cvt_pk_bf16(softplus_f(aA[2]), softplus_f(aA[3]))};
                *(u32x2a*)&hw[rowB + nt * 16 + q4] = u32x2{
                    cvt_pk_bf16(softplus_f(aB[0]), softplus_f(aB[1])),
                    cvt_pk_bf16(softplus_f(aB[2]), softplus_f(aB[3]))};
            }
        }
        // ---- rgb layer 1: K=64, out 64 ----
        {
            bf16x8 h0A = as_bf16x8(*(const u32x4a*)&hw[rowA + 0 + q * 8]);
            bf16x8 h1A = as_bf16x8(*(const u32x4a*)&hw[rowA + 32 + q * 8]);
            bf16x8 h0B = as_bf16x8(*(const u32x4a*)&hw[rowB + 0 + q * 8]);
            bf16x8 h1B = as_bf16x8(*(const u32x4a*)&hw[rowB + 32 + q * 8]);
#pragma unroll
            for (int nt = 0; nt < 4; ++nt) {
                bf16x8 w0 = as_bf16x8(*(const u32x4a*)&s_w[((26 + nt * 2 + 0) * 64 + lane) * 8]);
                bf16x8 w1 = as_bf16x8(*(const u32x4a*)&s_w[((26 + nt * 2 + 1) * 64 + lane) * 8]);
                f32x4 aA = __builtin_amdgcn_mfma_f32_16x16x32_bf16(w0, h0A, Bv[13 + nt], 0, 0, 0);
                aA = __builtin_amdgcn_mfma_f32_16x16x32_bf16(w1, h1A, aA, 0, 0, 0);
                f32x4 aB = __builtin_amdgcn_mfma_f32_16x16x32_bf16(w0, h0B, Bv[13 + nt], 0, 0, 0);
                aB = __builtin_amdgcn_mfma_f32_16x16x32_bf16(w1, h1B, aB, 0, 0, 0);
                *(u32x2a*)&hw[rowA + nt * 16 + q4] = u32x2{
                    cvt_pk_bf16(softplus_f(aA[0]), softplus_f(aA[1])),
                    cvt_pk_bf16(softplus_f(aA[2]), softplus_f(aA[3]))};
                *(u32x2a*)&hw[rowB + nt * 16 + q4] = u32x2{
                    cvt_pk_bf16(softplus_f(aB[0]), softplus_f(aB[1])),
                    cvt_pk_bf16(softplus_f(aB[2]), softplus_f(aB[3]))};
            }
        }
        // ---- rgb layer 2: K=64, outs 0..2 (sigmoid) + epilogue (both tiles) ----
        {
            bf16x8 h0A = as_bf16x8(*(const u32x4a*)&hw[rowA + 0 + q * 8]);
            bf16x8 h1A = as_bf16x8(*(const u32x4a*)&hw[rowA + 32 + q * 8]);
            bf16x8 h0B = as_bf16x8(*(const u32x4a*)&hw[rowB + 0 + q * 8]);
            bf16x8 h1B = as_bf16x8(*(const u32x4a*)&hw[rowB + 32 + q * 8]);
            bf16x8 w0 = as_bf16x8(*(const u32x4a*)&s_w[(34 * 64 + lane) * 8]);
            bf16x8 w1 = as_bf16x8(*(const u32x4a*)&s_w[(35 * 64 + lane) * 8]);
            f32x4 aA = __builtin_amdgcn_mfma_f32_16x16x32_bf16(w0, h0A, Bv[17], 0, 0, 0);
            aA = __builtin_amdgcn_mfma_f32_16x16x32_bf16(w1, h1A, aA, 0, 0, 0);
            f32x4 aB = __builtin_amdgcn_mfma_f32_16x16x32_bf16(w0, h0B, Bv[17], 0, 0, 0);
            aB = __builtin_amdgcn_mfma_f32_16x16x32_bf16(w1, h1B, aB, 0, 0, 0);
            if (q == 0) {
                f32x4 oA = {sigmoid_f(aA[0]), sigmoid_f(aA[1]), sigmoid_f(aA[2]), occA};
                f32x4 oB = {sigmoid_f(aB[0]), sigmoid_f(aB[1]), sigmoid_f(aB[2]), occB};
                *(f32x4a*)&out[ptA * 4] = oA;
                *(f32x4a*)&out[ptB * 4] = oB;
                out[(long)4 * n + ptA] = occA;
                out[(long)4 * n + ptB] = occB;
            }
        }
    }
}

extern "C" void kernel_launch(void* const* d_in, const int* in_sizes, int n_in,
                              void* d_out, int out_size, void* d_ws, size_t ws_size,
                              hipStream_t stream) {
    const int n = in_sizes[0] / 32;  // N = 524288
    float*  wsf = (float*)d_ws;
    ushort* wsw = (ushort*)((char*)d_ws + 1152);
    prep_weights<<<8, 256, 0, stream>>>(
        (const float*)d_in[2], (const float*)d_in[3],
        (const float*)d_in[4], (const float*)d_in[5],
        (const float*)d_in[6], (const float*)d_in[7],
        (const float*)d_in[8], (const float*)d_in[9],
        (const float*)d_in[10], (const float*)d_in[11],
        (const float*)d_in[12], (const float*)d_in[13],
        (const float*)d_in[14], (const int*)d_in[15],
        wsf, wsw);
    net_mfma<<<n / 1024, 256, 0, stream>>>(
        (const float*)d_in[0], (const float*)d_in[1],
        wsf, wsw, (float*)d_out, n);
}